// Round 3
// baseline (364.870 us; speedup 1.0000x reference)
//
#include <hip/hip_runtime.h>

constexpr int BS = 16;     // batch (vis and txt)
constexpr int S  = 4096;   // spatial 16*16*16
constexpr int E  = 128;    // embedding
constexpr int T  = 64;     // text tokens
constexpr int CH = 64;     // s-rows per chunk
constexpr int NSPLIT = 4;  // s-splits per (i,b) pair
constexpr int SSEG = S / NSPLIT;       // 1024
constexpr int NCH  = SSEG / CH;        // 16 chunks per block
constexpr int VTS = 72;    // Vt LDS stride (shorts)
constexpr int ETS = 68;    // ET LDS stride (shorts): 2-way (free) on scatter writes

// ws layout (floats):
//   [0..255]        sims[b*16+i]            (written by reduce kernel)
//   [256..1279]     denom[b*64+t]           (atomic-accumulated, diag splits)
//   [2048..)        wc^T partials: pair p = i*16+b -> 8192 floats [e][t] (atomic)
constexpr int WS_WC = 2048;
constexpr int WS_TOTAL = WS_WC + 256 * 8192;   // 2,099,200 floats = 8.4 MB

typedef __attribute__((ext_vector_type(8))) short bf16x8;
typedef __attribute__((ext_vector_type(4))) float f32x4;

__device__ __forceinline__ unsigned short f2bf(float x) {
    unsigned u = __float_as_uint(x);
    u += 0x7FFFu + ((u >> 16) & 1u);          // RTNE
    return (unsigned short)(u >> 16);
}
__device__ __forceinline__ float bf2f(unsigned short v) {
    return __uint_as_float(((unsigned)v) << 16);
}

__global__ __launch_bounds__(256, 4)
void ws_init_kernel(float* __restrict__ ws)
{
    const int idx = blockIdx.x * 256 + threadIdx.x;
    float4 z = {0.f, 0.f, 0.f, 0.f};
    // WS_TOTAL/4 = 524800 float4s; grid 512*256 = 131072 threads * 4 iters + tail
#pragma unroll
    for (int k = 0; k < 4; ++k) {
        const int j = idx + k * 131072;
        if (j < WS_TOTAL / 4) ((float4*)ws)[j] = z;
    }
}

// One block per (i, b, s-split). 256 threads = 4 waves, 4 blocks/CU.
__global__ __launch_bounds__(256, 4)
void clip_main_kernel(const float* __restrict__ vis,
                      const float* __restrict__ txt,
                      float* __restrict__ d_out,
                      float* __restrict__ ws)
{
    __shared__ unsigned short Vt[128 * VTS];  // Vt[e][s] bf16 (18.4 KB)
    __shared__ unsigned short ET[64 * ETS];   // et[t][s] bf16 (8.7 KB)
    __shared__ float invn[64];                // per-row inv L2 norms (current chunk)
    __shared__ float red[256];                // cross-wave reduce scratch

    const int tid = threadIdx.x;
    const int w   = tid >> 6;     // wave 0..3
    const int l   = tid & 63;
    const int cl  = l & 15;       // MFMA col lane
    const int q   = l >> 4;       // quad
    const int b   = blockIdx.x & 15;          // vis sample
    const int i   = (blockIdx.x >> 4) & 15;   // txt sample
    const int sp  = blockIdx.x >> 8;          // s-split 0..3
    const int p   = (i << 4) + b;             // pair index
    const bool diag = (i == b);

    // ---- setup: tn A-frags in registers (A[m=t: lane cl][k=e: q*8+j]) ----
    bf16x8 tA[4][4];   // [m-tile][k-step]
#pragma unroll
    for (int mt = 0; mt < 4; ++mt) {
        const float* tp = txt + ((long)i * T + mt * 16 + cl) * E + (q << 3);
        float x[4][8];
        float ssq = 0.f;
#pragma unroll
        for (int kk = 0; kk < 4; ++kk) {
            const float4 a0 = *(const float4*)(tp + (kk << 5));
            const float4 a1 = *(const float4*)(tp + (kk << 5) + 4);
            x[kk][0]=a0.x; x[kk][1]=a0.y; x[kk][2]=a0.z; x[kk][3]=a0.w;
            x[kk][4]=a1.x; x[kk][5]=a1.y; x[kk][6]=a1.z; x[kk][7]=a1.w;
#pragma unroll
            for (int j = 0; j < 8; ++j) ssq = fmaf(x[kk][j], x[kk][j], ssq);
        }
        ssq += __shfl_xor(ssq, 16);
        ssq += __shfl_xor(ssq, 32);
        const float inv = 1.0f / fmaxf(sqrtf(ssq), 1e-12f);
#pragma unroll
        for (int kk = 0; kk < 4; ++kk) {
            bf16x8 f;
#pragma unroll
            for (int j = 0; j < 8; ++j) f[j] = (short)f2bf(x[kk][j] * inv);
            tA[mt][kk] = f;
        }
    }

    f32x4 acc2[2][4];   // wc^T[e=w*32+mt2*16+q*4+r][t=n1*16+cl]
#pragma unroll
    for (int a = 0; a < 2; ++a)
#pragma unroll
        for (int n = 0; n < 4; ++n) acc2[a][n] = (f32x4){0.f, 0.f, 0.f, 0.f};
    float dnacc[16];
#pragma unroll
    for (int k = 0; k < 16; ++k) dnacc[k] = 0.f;

    const float* visb = vis + (long)b * S * E;
    float* attb = d_out + 1 + (long)b * (long)T * S;

    for (int ch = 0; ch < NCH; ++ch) {
        const int s0 = sp * SSEG + ch * CH;

        // ---- stage Vt[e][s] + invn (packed s-pairs; 2-way b32 writes, free) ----
        {
            const int pp = tid >> 3, ee = tid & 7;
            const float* rA = visb + (long)(s0 + (pp << 1)) * E + (ee << 1);
            float2 va[8], vb[8];
            float sa = 0.f, sb = 0.f;
#pragma unroll
            for (int k = 0; k < 8; ++k) {
                va[k] = *(const float2*)(rA + (k << 4));
                vb[k] = *(const float2*)(rA + E + (k << 4));
                sa = fmaf(va[k].x, va[k].x, fmaf(va[k].y, va[k].y, sa));
                sb = fmaf(vb[k].x, vb[k].x, fmaf(vb[k].y, vb[k].y, sb));
            }
            sa += __shfl_xor(sa, 1); sa += __shfl_xor(sa, 2); sa += __shfl_xor(sa, 4);
            sb += __shfl_xor(sb, 1); sb += __shfl_xor(sb, 2); sb += __shfl_xor(sb, 4);
            const float ia = 1.0f / fmaxf(sqrtf(sa), 1e-12f);
            const float ib = 1.0f / fmaxf(sqrtf(sb), 1e-12f);
            if (ee == 0) { invn[pp << 1] = ia; invn[(pp << 1) + 1] = ib; }
#pragma unroll
            for (int k = 0; k < 8; ++k) {
                const int e0 = (ee << 1) + (k << 4);
                unsigned lo = (unsigned)f2bf(va[k].x * ia) | ((unsigned)f2bf(vb[k].x * ib) << 16);
                unsigned hi = (unsigned)f2bf(va[k].y * ia) | ((unsigned)f2bf(vb[k].y * ib) << 16);
                *(unsigned*)&Vt[e0 * VTS + (pp << 1)]       = lo;
                *(unsigned*)&Vt[(e0 + 1) * VTS + (pp << 1)] = hi;
            }
        }
        __syncthreads();

        // ---- GEMM1: B-frags direct from global (normalized), MFMA vs tn regs ----
        f32x4 acc1[4];
#pragma unroll
        for (int mt = 0; mt < 4; ++mt) acc1[mt] = (f32x4){0.f, 0.f, 0.f, 0.f};
        {
            const float* rowp = visb + (long)(s0 + (w << 4) + cl) * E + (q << 3);
            const float invr = invn[(w << 4) + cl];
            bf16x8 Bf[4];
#pragma unroll
            for (int kk = 0; kk < 4; ++kk) {
                const float4 a0 = *(const float4*)(rowp + (kk << 5));
                const float4 a1 = *(const float4*)(rowp + (kk << 5) + 4);
                bf16x8 f;
                f[0]=(short)f2bf(a0.x*invr); f[1]=(short)f2bf(a0.y*invr);
                f[2]=(short)f2bf(a0.z*invr); f[3]=(short)f2bf(a0.w*invr);
                f[4]=(short)f2bf(a1.x*invr); f[5]=(short)f2bf(a1.y*invr);
                f[6]=(short)f2bf(a1.z*invr); f[7]=(short)f2bf(a1.w*invr);
                Bf[kk] = f;
            }
#pragma unroll
            for (int kk = 0; kk < 4; ++kk)
#pragma unroll
                for (int mt = 0; mt < 4; ++mt)
                    acc1[mt] = __builtin_amdgcn_mfma_f32_16x16x32_bf16(tA[mt][kk], Bf[kk], acc1[mt], 0, 0, 0);
        }

        // ---- softmax over t at own s-column; e = exp(4*s1); scatter to ET ----
        {
            float ex[4][4];
            float ssum = 0.f;
#pragma unroll
            for (int mt = 0; mt < 4; ++mt)
#pragma unroll
                for (int r = 0; r < 4; ++r) {
                    const float v = __expf(acc1[mt][r]);   // |logit| <= ~1
                    ex[mt][r] = v; ssum += v;
                }
            ssum += __shfl_xor(ssum, 16);
            ssum += __shfl_xor(ssum, 32);
            const float csc = 4.0f / ssum;
            const int sloc = (w << 4) + cl;
#pragma unroll
            for (int mt = 0; mt < 4; ++mt)
#pragma unroll
                for (int r = 0; r < 4; ++r) {
                    const float e = __expf(ex[mt][r] * csc);   // in [1, e^4]
                    ET[(mt * 16 + (q << 2) + r) * ETS + sloc] = f2bf(e);
                    dnacc[mt * 4 + r] += e;
                }
        }
        __syncthreads();

        // ---- GEMM2: wc^T[e][t] += Vt-frags x ET-frags ----
        {
            bf16x8 aV[2][2], bE[4][2];
#pragma unroll
            for (int mt2 = 0; mt2 < 2; ++mt2)
#pragma unroll
                for (int kk2 = 0; kk2 < 2; ++kk2)
                    aV[mt2][kk2] = *(const bf16x8*)&Vt[((w << 5) + (mt2 << 4) + cl) * VTS + (kk2 << 5) + (q << 3)];
#pragma unroll
            for (int n1 = 0; n1 < 4; ++n1)
#pragma unroll
                for (int kk2 = 0; kk2 < 2; ++kk2)
                    bE[n1][kk2] = *(const bf16x8*)&ET[((n1 << 4) + cl) * ETS + (kk2 << 5) + (q << 3)];
#pragma unroll
            for (int kk2 = 0; kk2 < 2; ++kk2)
#pragma unroll
                for (int mt2 = 0; mt2 < 2; ++mt2)
#pragma unroll
                    for (int n1 = 0; n1 < 4; ++n1)
                        acc2[mt2][n1] = __builtin_amdgcn_mfma_f32_16x16x32_bf16(aV[mt2][kk2], bE[n1][kk2], acc2[mt2][n1], 0, 0, 0);
        }

        // ---- diag: dump unnormalized e to att_maps (normalized by att_norm) ----
        if (diag) {
            const int t = tid >> 2, ssg = (tid & 3) << 4;
            float* ap = attb + (long)t * S + s0 + ssg;
#pragma unroll
            for (int j = 0; j < 16; ++j) ap[j] = bf2f(ET[t * ETS + ssg + j]);
        }
        __syncthreads();
    }

    // ---- diag: accumulate partial denominators denom[t] ----
    if (diag) {
        float d[16];
#pragma unroll
        for (int k = 0; k < 16; ++k) d[k] = dnacc[k];
#pragma unroll
        for (int k = 0; k < 16; ++k) {
            d[k] += __shfl_xor(d[k], 1); d[k] += __shfl_xor(d[k], 2);
            d[k] += __shfl_xor(d[k], 4); d[k] += __shfl_xor(d[k], 8);
        }
        if (cl == 0) {
#pragma unroll
            for (int mt = 0; mt < 4; ++mt)
#pragma unroll
                for (int r = 0; r < 4; ++r)
                    red[(w << 6) + mt * 16 + (q << 2) + r] = d[mt * 4 + r];
        }
        __syncthreads();
        if (tid < 64)
            atomicAdd(&ws[256 + b * 64 + tid],
                      red[tid] + red[64 + tid] + red[128 + tid] + red[192 + tid]);
    }

    // ---- dump wc^T partial via atomics (cross-split reduction) ----
    {
        float* wcb = ws + WS_WC + (long)p * 8192;
#pragma unroll
        for (int mt2 = 0; mt2 < 2; ++mt2)
#pragma unroll
            for (int n1 = 0; n1 < 4; ++n1)
#pragma unroll
                for (int r = 0; r < 4; ++r) {
                    const int e = (w << 5) + (mt2 << 4) + (q << 2) + r;
                    const int t = (n1 << 4) + cl;
                    atomicAdd(&wcb[e * 64 + t], acc2[mt2][n1][r]);
                }
    }
}

// One block per pair (i,b): cos over E, LSE over t -> sims[b][i].
__global__ __launch_bounds__(256, 4)
void reduce_kernel(const float* __restrict__ txt, float* __restrict__ ws)
{
    __shared__ float rA[256], rB[256], rC[256];
    const int tid = threadIdx.x;
    const int t = tid & 63, w = tid >> 6;
    const int pidx = blockIdx.x;
    const int i = pidx >> 4, b = pidx & 15;
    const float* wcb = ws + WS_WC + (long)pidx * 8192;
    const float* tp  = txt + ((long)i * T + t) * E + (w << 5);

    float ssq = 0.f, num = 0.f, w2 = 0.f;
#pragma unroll 8
    for (int e = 0; e < 32; ++e) {
        const float tv  = tp[e];
        const float wcv = wcb[((w << 5) + e) * 64 + t];
        ssq = fmaf(tv, tv, ssq);
        num = fmaf(wcv, tv, num);
        w2  = fmaf(wcv, wcv, w2);
    }
    rA[tid] = ssq; rB[tid] = num; rC[tid] = w2;
    __syncthreads();
    if (tid < 64) {
        const float ss = rA[tid] + rA[64 + tid] + rA[128 + tid] + rA[192 + tid];
        const float nm = rB[tid] + rB[64 + tid] + rB[128 + tid] + rB[192 + tid];
        const float ww = rC[tid] + rC[64 + tid] + rC[128 + tid] + rC[192 + tid];
        const float tinv = 1.0f / fmaxf(sqrtf(ss), 1e-12f);
        const float cosv = (nm * tinv) / fmaxf(sqrtf(ww), 1e-8f);  // denom cancels
        float r = __expf(5.0f * cosv);
#pragma unroll
        for (int m = 1; m < 64; m <<= 1) r += __shfl_xor(r, m);
        if (tid == 0) ws[b * 16 + i] = 10.0f * logf(r);
    }
}

// att_maps[b][t][:] *= 1/denom[b][t]. Region starts at d_out+1 (4B misaligned).
__global__ __launch_bounds__(256, 4)
void att_norm_kernel(float* __restrict__ d_out, const float* __restrict__ ws)
{
    const int bt = blockIdx.x;
    const float inv = 1.0f / ws[256 + bt];
    float* pout = d_out + 1 + (long)bt * 4096;
#pragma unroll
    for (int k = 0; k < 16; ++k)
        pout[k * 256 + threadIdx.x] *= inv;
}

// Final 16x16 symmetric cross-entropy.
__global__ __launch_bounds__(256, 1)
void loss_kernel(const float* __restrict__ ws, float* __restrict__ d_out)
{
    __shared__ float sm[16][17];
    __shared__ float red[16];
    const int tid = threadIdx.x;
    const int bb = tid >> 4, ii = tid & 15;
    const float x = ws[bb * 16 + ii];
    sm[bb][ii] = x;

    float m = x;
#pragma unroll
    for (int msk = 1; msk < 16; msk <<= 1) m = fmaxf(m, __shfl_xor(m, msk));
    float s = __expf(x - m);
#pragma unroll
    for (int msk = 1; msk < 16; msk <<= 1) s += __shfl_xor(s, msk);
    const float lsm0 = x - m - logf(s);

    __syncthreads();
    const float y = sm[ii][bb];
    float m1 = y;
#pragma unroll
    for (int msk = 1; msk < 16; msk <<= 1) m1 = fmaxf(m1, __shfl_xor(m1, msk));
    float s1 = __expf(y - m1);
#pragma unroll
    for (int msk = 1; msk < 16; msk <<= 1) s1 += __shfl_xor(s1, msk);
    const float lsm1 = y - m1 - logf(s1);

    if (bb == ii) red[bb] = lsm0 + lsm1;
    __syncthreads();
    if (tid == 0) {
        float tot = 0.f;
#pragma unroll
        for (int k = 0; k < 16; ++k) tot += red[k];
        d_out[0] = -tot / 32.0f;
    }
}

extern "C" void kernel_launch(void* const* d_in, const int* in_sizes, int n_in,
                              void* d_out, int out_size, void* d_ws, size_t ws_size,
                              hipStream_t stream)
{
    const float* vis = (const float*)d_in[0];
    const float* txt = (const float*)d_in[1];
    float* out = (float*)d_out;
    float* ws  = (float*)d_ws;

    hipLaunchKernelGGL(ws_init_kernel, dim3(512), dim3(256), 0, stream, ws);
    hipLaunchKernelGGL(clip_main_kernel, dim3(BS * BS * NSPLIT), dim3(256), 0, stream,
                       vis, txt, out, ws);
    hipLaunchKernelGGL(reduce_kernel, dim3(BS * BS), dim3(256), 0, stream, txt, ws);
    hipLaunchKernelGGL(att_norm_kernel, dim3(BS * T), dim3(256), 0, stream, out, ws);
    hipLaunchKernelGGL(loss_kernel, dim3(1), dim3(256), 0, stream, ws, out);
}

// Round 4
// 228.198 us; speedup vs baseline: 1.5989x; 1.5989x over previous
//
#include <hip/hip_runtime.h>

constexpr int BS = 16;     // batch (vis and txt)
constexpr int S  = 4096;   // spatial
constexpr int E  = 128;    // embedding
constexpr int T  = 64;     // text tokens
constexpr int CH = 256;    // s-rows per chunk
constexpr int NCH = S / CH;            // 16
constexpr int VTS = 264;   // Vt stride (shorts): 132 words = 4 mod 32, 16B-aligned rows
constexpr int ETS = 264;   // ET stride (shorts)
constexpr int TNS = 136;   // tnL stride (shorts): 68 words = 4 mod 32

typedef __attribute__((ext_vector_type(8))) short bf16x8;
typedef __attribute__((ext_vector_type(4))) float f32x4;

__device__ __forceinline__ unsigned short f2bf(float x) {
    unsigned u = __float_as_uint(x);
    u += 0x7FFFu + ((u >> 16) & 1u);          // RTNE
    return (unsigned short)(u >> 16);
}
__device__ __forceinline__ float bf2f(unsigned short v) {
    return __uint_as_float(((unsigned)v) << 16);
}

// One block per (i,b). 1024 threads = 16 waves = 4 waves/SIMD at 1 block/CU.
__global__ __launch_bounds__(1024, 4)
void clip_main_kernel(const float* __restrict__ vis,
                      const float* __restrict__ txt,
                      float* __restrict__ d_out,
                      float* __restrict__ ws)
{
    __shared__ unsigned short Vt[128 * VTS];  // vn^T[e][s] bf16   (67.6 KB)
    __shared__ unsigned short ET[T * ETS];    // e[t][s]   bf16    (33.8 KB)
    __shared__ unsigned short tnL[T * TNS];   // tn[t][e]  bf16    (17.4 KB)
    __shared__ float invn[CH];                // vis row inv-norms (chunk)
    __shared__ float sinvt[T];                // txt row inv-norms
    __shared__ float scr[1024];               // reduce scratch (denoms / num+w2)

    const int tid = threadIdx.x;
    const int w   = tid >> 6;       // wave 0..15
    const int l   = tid & 63;
    const int cl  = l & 15;
    const int q   = l >> 4;
    const int b   = blockIdx.x & 15;
    const int i   = blockIdx.x >> 4;
    const bool diag = (i == b);

    // ---- stage tn (normalized bf16) into LDS: row = tid>>4, 8-e segment = tid&15 ----
    {
        const int r   = tid >> 4;
        const int seg = tid & 15;
        const float* tp = txt + ((long)i * T + r) * E + (seg << 3);
        const float4 a0 = *(const float4*)(tp);
        const float4 a1 = *(const float4*)(tp + 4);
        float ssq = a0.x*a0.x + a0.y*a0.y + a0.z*a0.z + a0.w*a0.w
                  + a1.x*a1.x + a1.y*a1.y + a1.z*a1.z + a1.w*a1.w;
        ssq += __shfl_xor(ssq, 1); ssq += __shfl_xor(ssq, 2);
        ssq += __shfl_xor(ssq, 4); ssq += __shfl_xor(ssq, 8);
        const float inv = 1.0f / fmaxf(sqrtf(ssq), 1e-12f);
        if (seg == 0) sinvt[r] = inv;
        bf16x8 f;
        f[0]=(short)f2bf(a0.x*inv); f[1]=(short)f2bf(a0.y*inv);
        f[2]=(short)f2bf(a0.z*inv); f[3]=(short)f2bf(a0.w*inv);
        f[4]=(short)f2bf(a1.x*inv); f[5]=(short)f2bf(a1.y*inv);
        f[6]=(short)f2bf(a1.z*inv); f[7]=(short)f2bf(a1.w*inv);
        *(bf16x8*)&tnL[r * TNS + (seg << 3)] = f;
    }

    f32x4 acc2[2];         // wc^T tiles: e-tile et=w>>1, t-tiles nb, nb+1
    acc2[0] = (f32x4){0.f,0.f,0.f,0.f};
    acc2[1] = (f32x4){0.f,0.f,0.f,0.f};
    const int et = w >> 1;
    const int nb = (w & 1) << 1;
    float dn[16];
#pragma unroll
    for (int k = 0; k < 16; ++k) dn[k] = 0.f;

    const float* visb = vis + (long)b * S * E;
    float* attb = d_out + 1 + (long)b * (long)T * S;

    for (int ch = 0; ch < NCH; ++ch) {
        const int s0 = ch * CH;

        // ---- stage Vt[e][s] + invn: thread = 2 rows (pp) x 16 e's (ee), packed b32 ----
        {
            const int pp = tid >> 3, ee = tid & 7;
            const float* rA = visb + (long)(s0 + (pp << 1)) * E + (ee << 1);
            float2 va[8], vb[8];
            float sa = 0.f, sb = 0.f;
#pragma unroll
            for (int k = 0; k < 8; ++k) {
                va[k] = *(const float2*)(rA + (k << 4));
                vb[k] = *(const float2*)(rA + E + (k << 4));
                sa = fmaf(va[k].x, va[k].x, fmaf(va[k].y, va[k].y, sa));
                sb = fmaf(vb[k].x, vb[k].x, fmaf(vb[k].y, vb[k].y, sb));
            }
            sa += __shfl_xor(sa, 1); sa += __shfl_xor(sa, 2); sa += __shfl_xor(sa, 4);
            sb += __shfl_xor(sb, 1); sb += __shfl_xor(sb, 2); sb += __shfl_xor(sb, 4);
            const float ia = 1.0f / fmaxf(sqrtf(sa), 1e-12f);
            const float ib = 1.0f / fmaxf(sqrtf(sb), 1e-12f);
            if (ee == 0) { invn[pp << 1] = ia; invn[(pp << 1) + 1] = ib; }
#pragma unroll
            for (int k = 0; k < 8; ++k) {
                const int e0 = (ee << 1) + (k << 4);
                unsigned lo = (unsigned)f2bf(va[k].x * ia) | ((unsigned)f2bf(vb[k].x * ib) << 16);
                unsigned hi = (unsigned)f2bf(va[k].y * ia) | ((unsigned)f2bf(vb[k].y * ib) << 16);
                *(unsigned*)&Vt[e0 * VTS + (pp << 1)]       = lo;
                *(unsigned*)&Vt[(e0 + 1) * VTS + (pp << 1)] = hi;
            }
        }
        __syncthreads();

        // ---- GEMM1: D[t][s-slice of wave] ; A = tnL (LDS), B = vis row (global, L2-hot) ----
        f32x4 acc1[4];
#pragma unroll
        for (int mt = 0; mt < 4; ++mt) acc1[mt] = (f32x4){0.f,0.f,0.f,0.f};
        {
            const float* rowp = visb + (long)(s0 + (w << 4) + cl) * E + (q << 3);
            const float invr = invn[(w << 4) + cl];
#pragma unroll
            for (int kk = 0; kk < 4; ++kk) {
                const float4 a0 = *(const float4*)(rowp + (kk << 5));
                const float4 a1 = *(const float4*)(rowp + (kk << 5) + 4);
                bf16x8 Bf;
                Bf[0]=(short)f2bf(a0.x*invr); Bf[1]=(short)f2bf(a0.y*invr);
                Bf[2]=(short)f2bf(a0.z*invr); Bf[3]=(short)f2bf(a0.w*invr);
                Bf[4]=(short)f2bf(a1.x*invr); Bf[5]=(short)f2bf(a1.y*invr);
                Bf[6]=(short)f2bf(a1.z*invr); Bf[7]=(short)f2bf(a1.w*invr);
#pragma unroll
                for (int mt = 0; mt < 4; ++mt) {
                    const bf16x8 tAk = *(const bf16x8*)&tnL[((mt << 4) + cl) * TNS + (kk << 5) + (q << 3)];
                    acc1[mt] = __builtin_amdgcn_mfma_f32_16x16x32_bf16(tAk, Bf, acc1[mt], 0, 0, 0);
                }
            }
        }

        // ---- softmax over t at own s-col; e = exp(4*s1); scatter to ET ----
        {
            float ex[4][4];
            float ssum = 0.f;
#pragma unroll
            for (int mt = 0; mt < 4; ++mt)
#pragma unroll
                for (int r = 0; r < 4; ++r) {
                    const float v = __expf(acc1[mt][r]);   // |logit| <= ~1: no max needed
                    ex[mt][r] = v; ssum += v;
                }
            ssum += __shfl_xor(ssum, 16);
            ssum += __shfl_xor(ssum, 32);
            const float csc = 4.0f / ssum;
            const int sloc = (w << 4) + cl;
#pragma unroll
            for (int mt = 0; mt < 4; ++mt)
#pragma unroll
                for (int r = 0; r < 4; ++r) {
                    const float e = __expf(ex[mt][r] * csc);   // in [1, e^4]
                    ET[((mt << 4) + (q << 2) + r) * ETS + sloc] = f2bf(e);
                    dn[(mt << 2) + r] += e;
                }
        }
        __syncthreads();

        // ---- GEMM2: wc^T[e][t] += Vt x ET ; wave -> (e-tile et, t-tiles nb, nb+1) ----
#pragma unroll
        for (int kk2 = 0; kk2 < 8; ++kk2) {
            const bf16x8 aV  = *(const bf16x8*)&Vt[((et << 4) + cl) * VTS + (kk2 << 5) + (q << 3)];
            const bf16x8 bE0 = *(const bf16x8*)&ET[((nb << 4) + cl) * ETS + (kk2 << 5) + (q << 3)];
            const bf16x8 bE1 = *(const bf16x8*)&ET[(((nb + 1) << 4) + cl) * ETS + (kk2 << 5) + (q << 3)];
            acc2[0] = __builtin_amdgcn_mfma_f32_16x16x32_bf16(aV, bE0, acc2[0], 0, 0, 0);
            acc2[1] = __builtin_amdgcn_mfma_f32_16x16x32_bf16(aV, bE1, acc2[1], 0, 0, 0);
        }

        // ---- diag: dump unnormalized e to att region (normalized by att_norm) ----
        if (diag) {
            const int tb = (tid >> 8) << 4;
            const int sl = tid & 255;
#pragma unroll
            for (int j = 0; j < 16; ++j)
                attb[(long)(tb + j) * S + s0 + sl] = bf2f(ET[(tb + j) * ETS + sl]);
        }
        __syncthreads();
    }

    // ---- diag: reduce denom[t] = sum_s e (no atomics: unique block per b) ----
    if (diag) {
#pragma unroll
        for (int k = 0; k < 16; ++k) {
            dn[k] += __shfl_xor(dn[k], 1); dn[k] += __shfl_xor(dn[k], 2);
            dn[k] += __shfl_xor(dn[k], 4); dn[k] += __shfl_xor(dn[k], 8);
        }
        if (cl == 0) {
#pragma unroll
            for (int mt = 0; mt < 4; ++mt)
#pragma unroll
                for (int r = 0; r < 4; ++r)
                    scr[(w << 6) + (mt << 4) + (q << 2) + r] = dn[(mt << 2) + r];
        }
    }
    __syncthreads();
    if (diag && tid < 64) {
        float s = 0.f;
#pragma unroll
        for (int m = 0; m < 16; ++m) s += scr[(m << 6) + tid];
        ws[256 + (b << 6) + tid] = s;
    }
    __syncthreads();

    // ---- cosine + LSE over t (softmax denominator cancels analytically) ----
    {
        float pn[2] = {0.f, 0.f}, pw[2] = {0.f, 0.f};
        int tloc[2];
#pragma unroll
        for (int j = 0; j < 2; ++j) {
            const int t = ((nb + j) << 4) + cl;
            tloc[j] = t;
            const float tinv = sinvt[t];
            const float* tp = txt + ((long)i * T + t) * E + (et << 4) + (q << 2);
#pragma unroll
            for (int r = 0; r < 4; ++r) {
                const float wc = acc2[j][r];
                const float tv = tp[r] * tinv;
                pn[j] = fmaf(wc, tv, pn[j]);
                pw[j] = fmaf(wc, wc, pw[j]);
            }
        }
#pragma unroll
        for (int j = 0; j < 2; ++j) {
            pn[j] += __shfl_xor(pn[j], 16); pn[j] += __shfl_xor(pn[j], 32);
            pw[j] += __shfl_xor(pw[j], 16); pw[j] += __shfl_xor(pw[j], 32);
        }
        if (q == 0) {
#pragma unroll
            for (int j = 0; j < 2; ++j) {
                scr[(et << 6) + tloc[j]]       = pn[j];
                scr[512 + (et << 6) + tloc[j]] = pw[j];
            }
        }
        __syncthreads();
        if (tid < 64) {
            float num = 0.f, w2 = 0.f;
#pragma unroll
            for (int m = 0; m < 8; ++m) {
                num += scr[(m << 6) + tid];
                w2  += scr[512 + (m << 6) + tid];
            }
            const float cosv = num / fmaxf(sqrtf(w2), 1e-20f);  // ||tn||=1; dn cancels
            float r = __expf(5.0f * cosv);
#pragma unroll
            for (int m = 1; m < 64; m <<= 1) r += __shfl_xor(r, m);
            if (tid == 0) ws[(b << 4) + i] = 10.0f * logf(r);
        }
    }
}

// att_maps[b][t][:] *= 1/denom[b][t]. Region starts at d_out+1 (4B misaligned).
__global__ __launch_bounds__(256, 4)
void att_norm_kernel(float* __restrict__ d_out, const float* __restrict__ ws)
{
    const int bt = blockIdx.x;
    const float inv = 1.0f / ws[256 + bt];
    float* pout = d_out + 1 + (long)bt * 4096;
#pragma unroll
    for (int k = 0; k < 16; ++k)
        pout[k * 256 + threadIdx.x] *= inv;
}

// Final 16x16 symmetric cross-entropy.
__global__ __launch_bounds__(256, 1)
void loss_kernel(const float* __restrict__ ws, float* __restrict__ d_out)
{
    __shared__ float sm[16][17];
    __shared__ float red[16];
    const int tid = threadIdx.x;
    const int bb = tid >> 4, ii = tid & 15;
    const float x = ws[bb * 16 + ii];
    sm[bb][ii] = x;

    float m = x;
#pragma unroll
    for (int msk = 1; msk < 16; msk <<= 1) m = fmaxf(m, __shfl_xor(m, msk));
    float s = __expf(x - m);
#pragma unroll
    for (int msk = 1; msk < 16; msk <<= 1) s += __shfl_xor(s, msk);
    const float lsm0 = x - m - logf(s);

    __syncthreads();
    const float y = sm[ii][bb];
    float m1 = y;
#pragma unroll
    for (int msk = 1; msk < 16; msk <<= 1) m1 = fmaxf(m1, __shfl_xor(m1, msk));
    float s1 = __expf(y - m1);
#pragma unroll
    for (int msk = 1; msk < 16; msk <<= 1) s1 += __shfl_xor(s1, msk);
    const float lsm1 = y - m1 - logf(s1);

    if (bb == ii) red[bb] = lsm0 + lsm1;
    __syncthreads();
    if (tid == 0) {
        float tot = 0.f;
#pragma unroll
        for (int k = 0; k < 16; ++k) tot += red[k];
        d_out[0] = -tot / 32.0f;
    }
}

extern "C" void kernel_launch(void* const* d_in, const int* in_sizes, int n_in,
                              void* d_out, int out_size, void* d_ws, size_t ws_size,
                              hipStream_t stream)
{
    const float* vis = (const float*)d_in[0];
    const float* txt = (const float*)d_in[1];
    float* out = (float*)d_out;
    float* ws  = (float*)d_ws;   // [0..255] sims, [256..1279] diag denoms

    hipLaunchKernelGGL(clip_main_kernel, dim3(BS * BS), dim3(1024), 0, stream,
                       vis, txt, out, ws);
    hipLaunchKernelGGL(att_norm_kernel, dim3(BS * T), dim3(256), 0, stream, out, ws);
    hipLaunchKernelGGL(loss_kernel, dim3(1), dim3(256), 0, stream, ws, out);
}